// Round 5
// baseline (236.831 us; speedup 1.0000x reference)
//
#include <hip/hip_runtime.h>
#include <hip/hip_bf16.h>
#include <stdint.h>

typedef __bf16 bf16x8 __attribute__((ext_vector_type(8)));
typedef float f32x4 __attribute__((ext_vector_type(4)));
typedef unsigned short u16x8 __attribute__((ext_vector_type(8)));

#define ROUTE_BIAS_F 10.0f
#define VOCAB_SZ 32000

// ---------- helpers ----------
__device__ __forceinline__ unsigned short f2bf(float f) {
    union { float f; unsigned u; } v; v.f = f;
    unsigned u = v.u;
    unsigned r = u + 0x7FFFu + ((u >> 16) & 1u);   // RNE
    return (unsigned short)(r >> 16);
}
// async 16B global->LDS copy (lds dest wave-uniform; HW adds lane*16)
__device__ __forceinline__ void ld16(const unsigned short* g, unsigned short* l) {
    __builtin_amdgcn_global_load_lds(
        (const __attribute__((address_space(1))) void*)g,
        (__attribute__((address_space(3))) void*)l, 16, 0, 0);
}

// ---------- merged prep (router+convert) AND weight transpose ----------
// blocks [0, NPREP): one wave per token -> xb bf16 + eids.
// blocks [NPREP, NPREP+3072): 64x64 transpose+convert tiles of gup/dnp.
// Independent work merged into one launch: removes a launch gap and lets the
// VALU-ish prep co-schedule with the BW-bound transpose on the same CUs.
__global__ __launch_bounds__(256) void k_prep_all(
        const float* __restrict__ hidden, const float* __restrict__ mu,
        const int* __restrict__ tok_ids, const float* __restrict__ rw,
        const float* __restrict__ gup, const float* __restrict__ dnp,
        unsigned short* __restrict__ xb, int* __restrict__ eids,
        unsigned short* __restrict__ wgut, unsigned short* __restrict__ wdnt,
        int H, int N, int F2, int Ie, int NPREP) {
    __shared__ float tile[64][65];
    int bid = blockIdx.x;
    int tid = threadIdx.x;

    if (bid < NPREP) {
        // ---- prep path: 4 tokens per block, 1 wave per token ----
        int lane = tid & 63;
        int wv   = tid >> 6;
        int tok  = bid * 4 + wv;
        if (tok >= N) return;
        const float4* hp = (const float4*)(hidden + (size_t)tok * H);
        const float4* mp = (const float4*)(mu + (size_t)tok * H);
        const float4* rp = (const float4*)rw;            // [8][H/4]
        ushort4* xp = (ushort4*)(xb + (size_t)tok * H);
        int H4 = H >> 2;                                 // 256
        float acc[8];
#pragma unroll
        for (int e = 0; e < 8; ++e) acc[e] = 0.f;
#pragma unroll
        for (int j = 0; j < 4; ++j) {                    // H4/64 = 4
            int idx = lane + 64 * j;
            float4 h4 = hp[idx];
            ushort4 o;
            o.x = f2bf(h4.x); o.y = f2bf(h4.y); o.z = f2bf(h4.z); o.w = f2bf(h4.w);
            xp[idx] = o;
            float4 m4 = mp[idx];
#pragma unroll
            for (int e = 0; e < 8; ++e) {
                float4 w4 = rp[e * H4 + idx];
                acc[e] += m4.x * w4.x + m4.y * w4.y + m4.z * w4.z + m4.w * w4.w;
            }
        }
#pragma unroll
        for (int e = 0; e < 8; ++e) {
            float v = acc[e];
#pragma unroll
            for (int off = 32; off > 0; off >>= 1) v += __shfl_xor(v, off);
            acc[e] = v;
        }
        if (lane == 0) {
            int t = tok_ids[tok];
            if (t < 0) t = 0;
            if (t > VOCAB_SZ - 1) t = VOCAB_SZ - 1;
            int be = t % 8;
            float best = -1e30f; int bi = 0;
#pragma unroll
            for (int e = 0; e < 8; ++e) {
                float v = acc[e] + (e == be ? ROUTE_BIAS_F : 0.f);
                if (v > best) { best = v; bi = e; }
            }
            eids[tok] = bi;
        }
        return;
    }

    // ---- transpose path ----
    int tb = bid - NPREP;
    const float* inp; unsigned short* outp; int R, C, c0, r0;
    if (tb < 2048) {                      // gup: 8 experts x 256 tiles (16x16)
        int z = tb >> 8, t = tb & 255;
        R = H; C = F2;
        inp  = gup  + (size_t)z * R * C;
        outp = wgut + (size_t)z * R * C;  // [C][R]
        c0 = (t & 15) * 64; r0 = (t >> 4) * 64;
    } else {                              // dnp: 8 experts x 128 tiles (16x8)
        int tb2 = tb - 2048;
        int z = tb2 >> 7, t = tb2 & 127;
        R = Ie; C = H;
        inp  = dnp  + (size_t)z * R * C;
        outp = wdnt + (size_t)z * R * C;  // [C][R]
        c0 = (t & 15) * 64; r0 = (t >> 4) * 64;
    }
    {
        int tr = tid >> 4;              // 0..15
        int tc = (tid & 15) * 4;        // 0..60
#pragma unroll
        for (int p = 0; p < 4; ++p) {
            float4 v = *(const float4*)&inp[(size_t)(r0 + tr + 16 * p) * C + c0 + tc];
            tile[tr + 16 * p][tc + 0] = v.x;
            tile[tr + 16 * p][tc + 1] = v.y;
            tile[tr + 16 * p][tc + 2] = v.z;
            tile[tr + 16 * p][tc + 3] = v.w;
        }
        __syncthreads();
        int tr2 = tid >> 3;             // 0..31
        int tc2 = (tid & 7) * 8;        // 0..56
#pragma unroll
        for (int p = 0; p < 2; ++p) {
            int c = tr2 + 32 * p;
            u16x8 o;
#pragma unroll
            for (int j = 0; j < 8; ++j) o[j] = f2bf(tile[tc2 + j][c]);
            *(u16x8*)&outp[(size_t)(c0 + c) * R + r0 + tc2] = o;
        }
    }
}

// ---------- order-free compaction: ballot-aggregated atomic-cursor scatter ----
// Order within an expert is irrelevant (IT row = base+pos used consistently by
// both GEMMs), so no stable counting sort needed. Final cnt8[] values ARE the
// per-expert counts. cnt8 must be zeroed before this kernel (hipMemsetAsync).
__global__ void k_scatter(const int* __restrict__ eids,
                          int* __restrict__ cnt8,
                          int* __restrict__ list, int N) {
    int tid = threadIdx.x;
    int lane = tid & 63;
    int tok = blockIdx.x * 256 + tid;
    int eid = (tok < N) ? eids[tok] : -1;
    unsigned long long below = (1ull << lane) - 1ull;
#pragma unroll
    for (int e = 0; e < 8; ++e) {
        unsigned long long m = __ballot(eid == e);
        int old = 0;
        if (lane == 0 && m) old = atomicAdd(&cnt8[e], __popcll(m));
        old = __shfl(old, 0);
        if (eid == e) {
            int pos = old + __popcll(m & below);
            list[e * N + pos] = tok;
        }
    }
}

__global__ void k_scan_base(const int* __restrict__ cnt8, int* __restrict__ base_) {
    if (threadIdx.x == 0) {
        int s = 0;
#pragma unroll
        for (int i = 0; i < 8; ++i) { base_[i] = s; s += cnt8[i]; }
    }
}

// ---------- GEMM tile constants ----------
#define TM 128
#define TN 128
#define TK 64
// Counted-vmcnt depth-2 pipeline (T3+T4): per K-step
//   vmcnt(8) -> bar -> 16x ds_read_b128 frags -> lgkmcnt(0) -> bar
//   -> stage tile t+2 (8x ld16, stays in flight across MFMA) -> setprio(1)
//   -> 32 MFMA -> setprio(0).

// GEMM1 fused: IT[compact_row][Ie] = silu(gate)*up of gather(X) @ Wgu^T.
__global__ __launch_bounds__(256, 2) void k_gemm_gateup(
    const unsigned short* __restrict__ X,    // [N][H] bf16
    const unsigned short* __restrict__ Wt,   // [E][F2][H] bf16 (f-major)
    unsigned short* __restrict__ IT,         // [N][Ie] bf16 compact rows
    const int* __restrict__ counts, const int* __restrict__ base_,
    const int* __restrict__ list, int N, int H, int Ie) {
    int bid = blockIdx.x;
    int e = bid & 7;
    int t = bid >> 3;
    int nt = t & 7;                  // Ie/64 = 8 n-tiles
    int slot = t >> 3;               // 0..7
    int cnt = counts[e];
    int F2 = 2 * Ie;
    int b = base_[e];
    int nt64 = nt * 64;

    __shared__ __align__(16) unsigned short As[2][TM * TK];   // 2x16 KB
    __shared__ __align__(16) unsigned short Bs[2][TN * TK];   // 2x16 KB

    int tid = threadIdx.x;
    int lane = tid & 63, wv = tid >> 6;   // 4 waves
    int wr = (wv >> 1) * 64;
    int wc = (wv & 1) * 64;

    int rowg = lane >> 3;            // 0..7 row within 8-row group
    int sl   = (lane & 7) ^ rowg;    // swizzled source chunk for staging

    const unsigned short* bg[4];
#pragma unroll
    for (int i = 0; i < 4; ++i) {
        int r = wv * 32 + i * 8 + rowg;          // B tile row 0..127
        int wrow = (r & 1) * Ie + nt64 + (r >> 1);
        bg[i] = Wt + ((size_t)e * F2 + wrow) * H + sl * 8;
    }

    int q = lane >> 4, m = lane & 15;
    int sw = m & 7;
    int nk = H / TK;                 // 16

    for (int mt = slot; mt * TM < cnt; mt += 8) {
        int m0 = mt * TM;

        const unsigned short* ag[4];
#pragma unroll
        for (int i = 0; i < 4; ++i) {
            int r = wv * 32 + i * 8 + rowg;      // A tile row 0..127
            int gr = m0 + r;
            int tokrow = (gr < cnt) ? list[e * N + gr] : 0;
            ag[i] = X + (size_t)tokrow * H + sl * 8;
        }

        f32x4 acc[4][4];
#pragma unroll
        for (int i = 0; i < 4; ++i)
#pragma unroll
            for (int j = 0; j < 4; ++j) acc[i][j] = (f32x4)(0.f);

        // prologue: stage tile 0 -> buf0, tile 1 -> buf1 (16 loads in flight)
#pragma unroll
        for (int i = 0; i < 4; ++i) ld16(ag[i],      &As[0][(wv * 32 + i * 8) * TK]);
#pragma unroll
        for (int i = 0; i < 4; ++i) ld16(bg[i],      &Bs[0][(wv * 32 + i * 8) * TK]);
#pragma unroll
        for (int i = 0; i < 4; ++i) ld16(ag[i] + TK, &As[1][(wv * 32 + i * 8) * TK]);
#pragma unroll
        for (int i = 0; i < 4; ++i) ld16(bg[i] + TK, &Bs[1][(wv * 32 + i * 8) * TK]);

        for (int t_ = 0; t_ < nk; ++t_) {
            asm volatile("s_waitcnt vmcnt(8)" ::: "memory");
            __builtin_amdgcn_s_barrier();

            const unsigned short* Ac = As[t_ & 1];
            const unsigned short* Bc = Bs[t_ & 1];
            bf16x8 af[2][4], bfr[2][4];
#pragma unroll
            for (int s = 0; s < 2; ++s) {
                int ck = (((s * 4) + q) ^ sw) << 3;
#pragma unroll
                for (int im = 0; im < 4; ++im)
                    af[s][im] = *(const bf16x8*)&Ac[(wr + m + im * 16) * TK + ck];
#pragma unroll
                for (int in_ = 0; in_ < 4; ++in_)
                    bfr[s][in_] = *(const bf16x8*)&Bc[(wc + m + in_ * 16) * TK + ck];
            }
            asm volatile("s_waitcnt lgkmcnt(0)" ::: "memory");
            __builtin_amdgcn_s_barrier();   // all waves done reading buf[t_&1]

            int tn = t_ + 2; if (tn > nk - 1) tn = nk - 1;
            int kk = tn * TK;
#pragma unroll
            for (int i = 0; i < 4; ++i) ld16(ag[i] + kk, &As[t_ & 1][(wv * 32 + i * 8) * TK]);
#pragma unroll
            for (int i = 0; i < 4; ++i) ld16(bg[i] + kk, &Bs[t_ & 1][(wv * 32 + i * 8) * TK]);

            __builtin_amdgcn_s_setprio(1);
#pragma unroll
            for (int s = 0; s < 2; ++s)
#pragma unroll
                for (int im = 0; im < 4; ++im)
#pragma unroll
                    for (int in_ = 0; in_ < 4; ++in_)
                        acc[im][in_] = __builtin_amdgcn_mfma_f32_16x16x32_bf16(
                            af[s][im], bfr[s][in_], acc[im][in_], 0, 0, 0);
            __builtin_amdgcn_s_setprio(0);
        }
        asm volatile("s_waitcnt vmcnt(0)" ::: "memory");
        __builtin_amdgcn_s_barrier();

        // epilogue: pair even(gate)/odd(up) lanes, silu in fp32, write IT
#pragma unroll
        for (int im = 0; im < 4; ++im) {
#pragma unroll
            for (int j = 0; j < 4; ++j) {
                int row = wr + im * 16 + q * 4 + j;
                int gr = m0 + row;
#pragma unroll
                for (int in_ = 0; in_ < 4; ++in_) {
                    float v = acc[im][in_][j];
                    float u = __shfl_xor(v, 1);
                    float g = v;
                    float s = g / (1.f + __expf(-g));
                    float res = s * u;
                    if (!(lane & 1) && gr < cnt) {
                        int oc = nt64 + ((wc + in_ * 16 + m) >> 1);
                        IT[(size_t)(b + gr) * Ie + oc] = f2bf(res);
                    }
                }
            }
        }
    }
}

// GEMM2: OUT[token][H] = IT[compact_row][Ie] @ Wd^T, same pipeline.
__global__ __launch_bounds__(256, 2) void k_gemm_down(
    const unsigned short* __restrict__ IT,   // [N][Ie] bf16 compact
    const unsigned short* __restrict__ Wt,   // [E][H][Ie] bf16 (h-major)
    float* __restrict__ OUT,                 // [N][H] fp32 token-order
    const int* __restrict__ counts, const int* __restrict__ base_,
    const int* __restrict__ list, int N, int Ie, int H) {
    int bid = blockIdx.x;
    int e = bid & 7;
    int t = bid >> 3;
    int nt = t & 7;                  // H/TN = 8
    int slot = t >> 3;               // 0..7
    int cnt = counts[e];
    int n0 = nt * TN;
    int b = base_[e];

    __shared__ __align__(16) unsigned short As[2][TM * TK];
    __shared__ __align__(16) unsigned short Bs[2][TN * TK];

    int tid = threadIdx.x;
    int lane = tid & 63, wv = tid >> 6;
    int wr = (wv >> 1) * 64;
    int wc = (wv & 1) * 64;

    int rowg = lane >> 3;
    int sl   = (lane & 7) ^ rowg;

    const unsigned short* We = Wt + ((size_t)e * H + n0) * Ie;
    const unsigned short* bg[4];
#pragma unroll
    for (int i = 0; i < 4; ++i) {
        int r = wv * 32 + i * 8 + rowg;
        bg[i] = We + (size_t)r * Ie + sl * 8;
    }

    int q = lane >> 4, m = lane & 15;
    int sw = m & 7;
    int nk = Ie / TK;                // 8

    for (int mt = slot; mt * TM < cnt; mt += 8) {
        int m0 = mt * TM;

        const unsigned short* ag[4];
#pragma unroll
        for (int i = 0; i < 4; ++i) {
            int r = wv * 32 + i * 8 + rowg;
            int gr = m0 + r;
            int arow = (gr < cnt) ? (b + gr) : b;
            ag[i] = IT + (size_t)arow * Ie + sl * 8;
        }

        f32x4 acc[4][4];
#pragma unroll
        for (int i = 0; i < 4; ++i)
#pragma unroll
            for (int j = 0; j < 4; ++j) acc[i][j] = (f32x4)(0.f);

#pragma unroll
        for (int i = 0; i < 4; ++i) ld16(ag[i],      &As[0][(wv * 32 + i * 8) * TK]);
#pragma unroll
        for (int i = 0; i < 4; ++i) ld16(bg[i],      &Bs[0][(wv * 32 + i * 8) * TK]);
#pragma unroll
        for (int i = 0; i < 4; ++i) ld16(ag[i] + TK, &As[1][(wv * 32 + i * 8) * TK]);
#pragma unroll
        for (int i = 0; i < 4; ++i) ld16(bg[i] + TK, &Bs[1][(wv * 32 + i * 8) * TK]);

        for (int t_ = 0; t_ < nk; ++t_) {
            asm volatile("s_waitcnt vmcnt(8)" ::: "memory");
            __builtin_amdgcn_s_barrier();

            const unsigned short* Ac = As[t_ & 1];
            const unsigned short* Bc = Bs[t_ & 1];
            bf16x8 af[2][4], bfr[2][4];
#pragma unroll
            for (int s = 0; s < 2; ++s) {
                int ck = (((s * 4) + q) ^ sw) << 3;
#pragma unroll
                for (int im = 0; im < 4; ++im)
                    af[s][im] = *(const bf16x8*)&Ac[(wr + m + im * 16) * TK + ck];
#pragma unroll
                for (int in_ = 0; in_ < 4; ++in_)
                    bfr[s][in_] = *(const bf16x8*)&Bc[(wc + m + in_ * 16) * TK + ck];
            }
            asm volatile("s_waitcnt lgkmcnt(0)" ::: "memory");
            __builtin_amdgcn_s_barrier();

            int tn = t_ + 2; if (tn > nk - 1) tn = nk - 1;
            int kk = tn * TK;
#pragma unroll
            for (int i = 0; i < 4; ++i) ld16(ag[i] + kk, &As[t_ & 1][(wv * 32 + i * 8) * TK]);
#pragma unroll
            for (int i = 0; i < 4; ++i) ld16(bg[i] + kk, &Bs[t_ & 1][(wv * 32 + i * 8) * TK]);

            __builtin_amdgcn_s_setprio(1);
#pragma unroll
            for (int s = 0; s < 2; ++s)
#pragma unroll
                for (int im = 0; im < 4; ++im)
#pragma unroll
                    for (int in_ = 0; in_ < 4; ++in_)
                        acc[im][in_] = __builtin_amdgcn_mfma_f32_16x16x32_bf16(
                            af[s][im], bfr[s][in_], acc[im][in_], 0, 0, 0);
            __builtin_amdgcn_s_setprio(0);
        }
        asm volatile("s_waitcnt vmcnt(0)" ::: "memory");
        __builtin_amdgcn_s_barrier();

#pragma unroll
        for (int im = 0; im < 4; ++im) {
#pragma unroll
            for (int j = 0; j < 4; ++j) {
                int row = wr + im * 16 + q * 4 + j;
                int gr = m0 + row;
                if (gr < cnt) {
                    int tok = list[e * N + gr];
                    float* orow = OUT + (size_t)tok * H + n0;
#pragma unroll
                    for (int in_ = 0; in_ < 4; ++in_) {
                        int col = wc + in_ * 16 + m;
                        orow[col] = acc[im][in_][j];
                    }
                }
            }
        }
    }
}

extern "C" void kernel_launch(void* const* d_in, const int* in_sizes, int n_in,
                              void* d_out, int out_size, void* d_ws, size_t ws_size,
                              hipStream_t stream) {
    const float* hidden   = (const float*)d_in[0];
    const int*   tok_ids  = (const int*)d_in[1];
    const float* mu       = (const float*)d_in[2];
    const float* gup      = (const float*)d_in[3];
    const float* dnp      = (const float*)d_in[4];
    const float* rw       = (const float*)d_in[5];
    float* out = (float*)d_out;

    int N  = in_sizes[1];                 // 8192
    int H  = in_sizes[0] / N;             // 1024
    int E  = in_sizes[5] / H;             // 8
    int F2 = in_sizes[3] / (E * H);       // 1024
    int Ie = F2 / 2;                      // 512

    char* ws = (char*)d_ws;
    size_t o = 0;
    auto alloc = [&](size_t sz) {
        size_t r = o;
        o += (sz + 255) & ~(size_t)255;
        return r;
    };
    int* cnt8     = (int*)(ws + alloc((size_t)E * 4));   // atomic cursors -> counts
    int* base_    = (int*)(ws + alloc((size_t)E * 4));
    int* eids     = (int*)(ws + alloc((size_t)N * 4));
    int* list     = (int*)(ws + alloc((size_t)E * N * 4));
    unsigned short* xb   = (unsigned short*)(ws + alloc((size_t)N * H * 2));
    unsigned short* wgut = (unsigned short*)(ws + alloc((size_t)E * F2 * H * 2));
    unsigned short* wdnt = (unsigned short*)(ws + alloc((size_t)E * H * Ie * 2));
    unsigned short* it   = (unsigned short*)(ws + alloc((size_t)N * Ie * 2));

    // zero the atomic cursors (workspace is poisoned, not zeroed, each run)
    hipMemsetAsync(cnt8, 0, (size_t)E * 4, stream);

    int NPREP = (N + 3) / 4;              // 2048
    int NTRANS = 2048 + 1024;             // gup tiles + dnp tiles
    k_prep_all<<<dim3(NPREP + NTRANS), dim3(256), 0, stream>>>(
        hidden, mu, tok_ids, rw, gup, dnp, xb, eids, wgut, wdnt, H, N, F2, Ie, NPREP);

    int NB = (N + 255) / 256;             // 32
    k_scatter<<<dim3(NB), dim3(256), 0, stream>>>(eids, cnt8, list, N);
    k_scan_base<<<dim3(1), dim3(64), 0, stream>>>(cnt8, base_);

    // exact grids: 8 experts x (n-tiles) x 8 slots; slot-blocks loop over mt
    k_gemm_gateup<<<dim3(E * (Ie / 64) * 8), dim3(256), 0, stream>>>(
        xb, wgut, it, cnt8, base_, list, N, H, Ie);

    k_gemm_down<<<dim3(E * (H / TN) * 8), dim3(256), 0, stream>>>(
        it, wdnt, out, cnt8, base_, list, N, Ie, H);
}

// Round 6
// 230.269 us; speedup vs baseline: 1.0285x; 1.0285x over previous
//
#include <hip/hip_runtime.h>
#include <hip/hip_bf16.h>
#include <stdint.h>

typedef __bf16 bf16x8 __attribute__((ext_vector_type(8)));
typedef float f32x4 __attribute__((ext_vector_type(4)));
typedef unsigned short u16x8 __attribute__((ext_vector_type(8)));

#define ROUTE_BIAS_F 10.0f
#define VOCAB_SZ 32000

// ---------- helpers ----------
__device__ __forceinline__ unsigned short f2bf(float f) {
    union { float f; unsigned u; } v; v.f = f;
    unsigned u = v.u;
    unsigned r = u + 0x7FFFu + ((u >> 16) & 1u);   // RNE
    return (unsigned short)(r >> 16);
}
// async 16B global->LDS copy (lds dest wave-uniform; HW adds lane*16)
__device__ __forceinline__ void ld16(const unsigned short* g, unsigned short* l) {
    __builtin_amdgcn_global_load_lds(
        (const __attribute__((address_space(1))) void*)g,
        (__attribute__((address_space(3))) void*)l, 16, 0, 0);
}

// ---------- merged prep (router+convert) AND weight transpose ----------
// blocks [0, NPREP): one wave per token -> xb bf16 + eids.
// blocks [NPREP, NPREP+3072): 64x64 transpose+convert tiles of gup/dnp.
__global__ __launch_bounds__(256) void k_prep_all(
        const float* __restrict__ hidden, const float* __restrict__ mu,
        const int* __restrict__ tok_ids, const float* __restrict__ rw,
        const float* __restrict__ gup, const float* __restrict__ dnp,
        unsigned short* __restrict__ xb, int* __restrict__ eids,
        unsigned short* __restrict__ wgut, unsigned short* __restrict__ wdnt,
        int H, int N, int F2, int Ie, int NPREP) {
    __shared__ float tile[64][65];
    int bid = blockIdx.x;
    int tid = threadIdx.x;

    if (bid < NPREP) {
        // ---- prep path: 4 tokens per block, 1 wave per token ----
        int lane = tid & 63;
        int wv   = tid >> 6;
        int tok  = bid * 4 + wv;
        if (tok >= N) return;
        const float4* hp = (const float4*)(hidden + (size_t)tok * H);
        const float4* mp = (const float4*)(mu + (size_t)tok * H);
        const float4* rp = (const float4*)rw;            // [8][H/4]
        ushort4* xp = (ushort4*)(xb + (size_t)tok * H);
        int H4 = H >> 2;                                 // 256
        float acc[8];
#pragma unroll
        for (int e = 0; e < 8; ++e) acc[e] = 0.f;
#pragma unroll
        for (int j = 0; j < 4; ++j) {                    // H4/64 = 4
            int idx = lane + 64 * j;
            float4 h4 = hp[idx];
            ushort4 o;
            o.x = f2bf(h4.x); o.y = f2bf(h4.y); o.z = f2bf(h4.z); o.w = f2bf(h4.w);
            xp[idx] = o;
            float4 m4 = mp[idx];
#pragma unroll
            for (int e = 0; e < 8; ++e) {
                float4 w4 = rp[e * H4 + idx];
                acc[e] += m4.x * w4.x + m4.y * w4.y + m4.z * w4.z + m4.w * w4.w;
            }
        }
#pragma unroll
        for (int e = 0; e < 8; ++e) {
            float v = acc[e];
#pragma unroll
            for (int off = 32; off > 0; off >>= 1) v += __shfl_xor(v, off);
            acc[e] = v;
        }
        if (lane == 0) {
            int t = tok_ids[tok];
            if (t < 0) t = 0;
            if (t > VOCAB_SZ - 1) t = VOCAB_SZ - 1;
            int be = t % 8;
            float best = -1e30f; int bi = 0;
#pragma unroll
            for (int e = 0; e < 8; ++e) {
                float v = acc[e] + (e == be ? ROUTE_BIAS_F : 0.f);
                if (v > best) { best = v; bi = e; }
            }
            eids[tok] = bi;
        }
        return;
    }

    // ---- transpose path ----
    int tb = bid - NPREP;
    const float* inp; unsigned short* outp; int R, C, c0, r0;
    if (tb < 2048) {                      // gup: 8 experts x 256 tiles (16x16)
        int z = tb >> 8, t = tb & 255;
        R = H; C = F2;
        inp  = gup  + (size_t)z * R * C;
        outp = wgut + (size_t)z * R * C;  // [C][R]
        c0 = (t & 15) * 64; r0 = (t >> 4) * 64;
    } else {                              // dnp: 8 experts x 128 tiles (16x8)
        int tb2 = tb - 2048;
        int z = tb2 >> 7, t = tb2 & 127;
        R = Ie; C = H;
        inp  = dnp  + (size_t)z * R * C;
        outp = wdnt + (size_t)z * R * C;  // [C][R]
        c0 = (t & 15) * 64; r0 = (t >> 4) * 64;
    }
    {
        int tr = tid >> 4;              // 0..15
        int tc = (tid & 15) * 4;        // 0..60
#pragma unroll
        for (int p = 0; p < 4; ++p) {
            float4 v = *(const float4*)&inp[(size_t)(r0 + tr + 16 * p) * C + c0 + tc];
            tile[tr + 16 * p][tc + 0] = v.x;
            tile[tr + 16 * p][tc + 1] = v.y;
            tile[tr + 16 * p][tc + 2] = v.z;
            tile[tr + 16 * p][tc + 3] = v.w;
        }
        __syncthreads();
        int tr2 = tid >> 3;             // 0..31
        int tc2 = (tid & 7) * 8;        // 0..56
#pragma unroll
        for (int p = 0; p < 2; ++p) {
            int c = tr2 + 32 * p;
            u16x8 o;
#pragma unroll
            for (int j = 0; j < 8; ++j) o[j] = f2bf(tile[tc2 + j][c]);
            *(u16x8*)&outp[(size_t)(c0 + c) * R + r0 + tc2] = o;
        }
    }
}

// ---------- router phase B: STABLE parallel counting sort ----------
// Token-sorted per-expert lists are a PERF CONTRACT with the GEMMs: the
// A-gather (GEMM1) and OUT scatter (GEMM2) walk near-sequential rows only if
// the list is token-ordered. (Round-5 order-free atomic scatter: +19us on
// gateup from L2-miss latency on random gathers.)
__global__ void k_count(const int* __restrict__ eids,
                        int* __restrict__ blockcnt, int N) {
    __shared__ int cnt[8];
    int tid = threadIdx.x;
    if (tid < 8) cnt[tid] = 0;
    __syncthreads();
    int tok = blockIdx.x * 256 + tid;
    int lane = tid & 63;
    int eid = (tok < N) ? eids[tok] : -1;
#pragma unroll
    for (int e = 0; e < 8; ++e) {
        unsigned long long m = __ballot(eid == e);
        if (lane == 0 && m) atomicAdd(&cnt[e], __popcll(m));
    }
    __syncthreads();
    if (tid < 8) blockcnt[blockIdx.x * 8 + tid] = cnt[tid];
}

__global__ void k_scan(const int* __restrict__ blockcnt,
                       int* __restrict__ counts, int* __restrict__ base_,
                       int* __restrict__ offs, int NB) {   // NB == 32
    __shared__ int tot[8];
    int lane = threadIdx.x;
    int e = lane >> 3, g = lane & 7;
    int v[4];
    int s = 0;
#pragma unroll
    for (int i = 0; i < 4; ++i) { v[i] = s; s += blockcnt[(g * 4 + i) * 8 + e]; }
    int inc = s;
#pragma unroll
    for (int d = 1; d < 8; d <<= 1) {
        int t = __shfl_up(inc, d);
        if (g >= d) inc += t;
    }
    int excl = inc - s;
#pragma unroll
    for (int i = 0; i < 4; ++i) offs[(g * 4 + i) * 8 + e] = excl + v[i];
    if (g == 7) { counts[e] = inc; tot[e] = inc; }
    __syncthreads();
    if (lane == 0) {
        int s2 = 0;
#pragma unroll
        for (int i = 0; i < 8; ++i) { base_[i] = s2; s2 += tot[i]; }
    }
}

__global__ void k_scatter(const int* __restrict__ eids,
                          const int* __restrict__ offs,
                          int* __restrict__ list, int N) {
    __shared__ int wavecnt[4][8];
    int tid = threadIdx.x;
    int lane = tid & 63, wv = tid >> 6;
    int tok = blockIdx.x * 256 + tid;
    int eid = (tok < N) ? eids[tok] : -1;
    unsigned long long below = (1ull << lane) - 1ull;
    int myrank = 0;
#pragma unroll
    for (int e = 0; e < 8; ++e) {
        unsigned long long m = __ballot(eid == e);
        if (lane == 0) wavecnt[wv][e] = __popcll(m);
        if (eid == e) myrank = __popcll(m & below);
    }
    __syncthreads();
    if (eid >= 0) {
        int pre = 0;
        for (int w = 0; w < wv; ++w) pre += wavecnt[w][eid];
        int pos = offs[blockIdx.x * 8 + eid] + pre + myrank;
        list[eid * N + pos] = tok;
    }
}

// ---------- GEMM tile constants ----------
#define TM 128
#define TN 128
#define TK 64
// Counted-vmcnt depth-2 pipeline (T3+T4): per K-step
//   vmcnt(8) -> bar -> 16x ds_read_b128 frags -> lgkmcnt(0) -> bar
//   -> stage tile t+2 (8x ld16, stays in flight across MFMA) -> setprio(1)
//   -> 32 MFMA -> setprio(0).

// GEMM1 fused: IT[compact_row][Ie] = silu(gate)*up of gather(X) @ Wgu^T.
__global__ __launch_bounds__(256, 2) void k_gemm_gateup(
    const unsigned short* __restrict__ X,    // [N][H] bf16
    const unsigned short* __restrict__ Wt,   // [E][F2][H] bf16 (f-major)
    unsigned short* __restrict__ IT,         // [N][Ie] bf16 compact rows
    const int* __restrict__ counts, const int* __restrict__ base_,
    const int* __restrict__ list, int N, int H, int Ie) {
    int bid = blockIdx.x;
    int e = bid & 7;
    int t = bid >> 3;
    int nt = t & 7;                  // Ie/64 = 8 n-tiles
    int slot = t >> 3;               // 0..7
    int cnt = counts[e];
    int F2 = 2 * Ie;
    int b = base_[e];
    int nt64 = nt * 64;

    __shared__ __align__(16) unsigned short As[2][TM * TK];   // 2x16 KB
    __shared__ __align__(16) unsigned short Bs[2][TN * TK];   // 2x16 KB

    int tid = threadIdx.x;
    int lane = tid & 63, wv = tid >> 6;   // 4 waves
    int wr = (wv >> 1) * 64;
    int wc = (wv & 1) * 64;

    int rowg = lane >> 3;            // 0..7 row within 8-row group
    int sl   = (lane & 7) ^ rowg;    // swizzled source chunk for staging

    const unsigned short* bg[4];
#pragma unroll
    for (int i = 0; i < 4; ++i) {
        int r = wv * 32 + i * 8 + rowg;          // B tile row 0..127
        int wrow = (r & 1) * Ie + nt64 + (r >> 1);
        bg[i] = Wt + ((size_t)e * F2 + wrow) * H + sl * 8;
    }

    int q = lane >> 4, m = lane & 15;
    int sw = m & 7;
    int nk = H / TK;                 // 16

    for (int mt = slot; mt * TM < cnt; mt += 8) {
        int m0 = mt * TM;

        const unsigned short* ag[4];
#pragma unroll
        for (int i = 0; i < 4; ++i) {
            int r = wv * 32 + i * 8 + rowg;      // A tile row 0..127
            int gr = m0 + r;
            int tokrow = (gr < cnt) ? list[e * N + gr] : 0;
            ag[i] = X + (size_t)tokrow * H + sl * 8;
        }

        f32x4 acc[4][4];
#pragma unroll
        for (int i = 0; i < 4; ++i)
#pragma unroll
            for (int j = 0; j < 4; ++j) acc[i][j] = (f32x4)(0.f);

        // prologue: stage tile 0 -> buf0, tile 1 -> buf1 (16 loads in flight)
#pragma unroll
        for (int i = 0; i < 4; ++i) ld16(ag[i],      &As[0][(wv * 32 + i * 8) * TK]);
#pragma unroll
        for (int i = 0; i < 4; ++i) ld16(bg[i],      &Bs[0][(wv * 32 + i * 8) * TK]);
#pragma unroll
        for (int i = 0; i < 4; ++i) ld16(ag[i] + TK, &As[1][(wv * 32 + i * 8) * TK]);
#pragma unroll
        for (int i = 0; i < 4; ++i) ld16(bg[i] + TK, &Bs[1][(wv * 32 + i * 8) * TK]);

        for (int t_ = 0; t_ < nk; ++t_) {
            asm volatile("s_waitcnt vmcnt(8)" ::: "memory");
            __builtin_amdgcn_s_barrier();

            const unsigned short* Ac = As[t_ & 1];
            const unsigned short* Bc = Bs[t_ & 1];
            bf16x8 af[2][4], bfr[2][4];
#pragma unroll
            for (int s = 0; s < 2; ++s) {
                int ck = (((s * 4) + q) ^ sw) << 3;
#pragma unroll
                for (int im = 0; im < 4; ++im)
                    af[s][im] = *(const bf16x8*)&Ac[(wr + m + im * 16) * TK + ck];
#pragma unroll
                for (int in_ = 0; in_ < 4; ++in_)
                    bfr[s][in_] = *(const bf16x8*)&Bc[(wc + m + in_ * 16) * TK + ck];
            }
            asm volatile("s_waitcnt lgkmcnt(0)" ::: "memory");
            __builtin_amdgcn_s_barrier();   // all waves done reading buf[t_&1]

            int tn = t_ + 2; if (tn > nk - 1) tn = nk - 1;
            int kk = tn * TK;
#pragma unroll
            for (int i = 0; i < 4; ++i) ld16(ag[i] + kk, &As[t_ & 1][(wv * 32 + i * 8) * TK]);
#pragma unroll
            for (int i = 0; i < 4; ++i) ld16(bg[i] + kk, &Bs[t_ & 1][(wv * 32 + i * 8) * TK]);

            __builtin_amdgcn_s_setprio(1);
#pragma unroll
            for (int s = 0; s < 2; ++s)
#pragma unroll
                for (int im = 0; im < 4; ++im)
#pragma unroll
                    for (int in_ = 0; in_ < 4; ++in_)
                        acc[im][in_] = __builtin_amdgcn_mfma_f32_16x16x32_bf16(
                            af[s][im], bfr[s][in_], acc[im][in_], 0, 0, 0);
            __builtin_amdgcn_s_setprio(0);
        }
        asm volatile("s_waitcnt vmcnt(0)" ::: "memory");
        __builtin_amdgcn_s_barrier();

        // epilogue: pair even(gate)/odd(up) lanes, silu in fp32, write IT
#pragma unroll
        for (int im = 0; im < 4; ++im) {
#pragma unroll
            for (int j = 0; j < 4; ++j) {
                int row = wr + im * 16 + q * 4 + j;
                int gr = m0 + row;
#pragma unroll
                for (int in_ = 0; in_ < 4; ++in_) {
                    float v = acc[im][in_][j];
                    float u = __shfl_xor(v, 1);
                    float g = v;
                    float s = g / (1.f + __expf(-g));
                    float res = s * u;
                    if (!(lane & 1) && gr < cnt) {
                        int oc = nt64 + ((wc + in_ * 16 + m) >> 1);
                        IT[(size_t)(b + gr) * Ie + oc] = f2bf(res);
                    }
                }
            }
        }
    }
}

// GEMM2: OUT[token][H] = IT[compact_row][Ie] @ Wd^T, same pipeline.
__global__ __launch_bounds__(256, 2) void k_gemm_down(
    const unsigned short* __restrict__ IT,   // [N][Ie] bf16 compact
    const unsigned short* __restrict__ Wt,   // [E][H][Ie] bf16 (h-major)
    float* __restrict__ OUT,                 // [N][H] fp32 token-order
    const int* __restrict__ counts, const int* __restrict__ base_,
    const int* __restrict__ list, int N, int Ie, int H) {
    int bid = blockIdx.x;
    int e = bid & 7;
    int t = bid >> 3;
    int nt = t & 7;                  // H/TN = 8
    int slot = t >> 3;               // 0..7
    int cnt = counts[e];
    int n0 = nt * TN;
    int b = base_[e];

    __shared__ __align__(16) unsigned short As[2][TM * TK];
    __shared__ __align__(16) unsigned short Bs[2][TN * TK];

    int tid = threadIdx.x;
    int lane = tid & 63, wv = tid >> 6;
    int wr = (wv >> 1) * 64;
    int wc = (wv & 1) * 64;

    int rowg = lane >> 3;
    int sl   = (lane & 7) ^ rowg;

    const unsigned short* We = Wt + ((size_t)e * H + n0) * Ie;
    const unsigned short* bg[4];
#pragma unroll
    for (int i = 0; i < 4; ++i) {
        int r = wv * 32 + i * 8 + rowg;
        bg[i] = We + (size_t)r * Ie + sl * 8;
    }

    int q = lane >> 4, m = lane & 15;
    int sw = m & 7;
    int nk = Ie / TK;                // 8

    for (int mt = slot; mt * TM < cnt; mt += 8) {
        int m0 = mt * TM;

        const unsigned short* ag[4];
#pragma unroll
        for (int i = 0; i < 4; ++i) {
            int r = wv * 32 + i * 8 + rowg;
            int gr = m0 + r;
            int arow = (gr < cnt) ? (b + gr) : b;
            ag[i] = IT + (size_t)arow * Ie + sl * 8;
        }

        f32x4 acc[4][4];
#pragma unroll
        for (int i = 0; i < 4; ++i)
#pragma unroll
            for (int j = 0; j < 4; ++j) acc[i][j] = (f32x4)(0.f);

#pragma unroll
        for (int i = 0; i < 4; ++i) ld16(ag[i],      &As[0][(wv * 32 + i * 8) * TK]);
#pragma unroll
        for (int i = 0; i < 4; ++i) ld16(bg[i],      &Bs[0][(wv * 32 + i * 8) * TK]);
#pragma unroll
        for (int i = 0; i < 4; ++i) ld16(ag[i] + TK, &As[1][(wv * 32 + i * 8) * TK]);
#pragma unroll
        for (int i = 0; i < 4; ++i) ld16(bg[i] + TK, &Bs[1][(wv * 32 + i * 8) * TK]);

        for (int t_ = 0; t_ < nk; ++t_) {
            asm volatile("s_waitcnt vmcnt(8)" ::: "memory");
            __builtin_amdgcn_s_barrier();

            const unsigned short* Ac = As[t_ & 1];
            const unsigned short* Bc = Bs[t_ & 1];
            bf16x8 af[2][4], bfr[2][4];
#pragma unroll
            for (int s = 0; s < 2; ++s) {
                int ck = (((s * 4) + q) ^ sw) << 3;
#pragma unroll
                for (int im = 0; im < 4; ++im)
                    af[s][im] = *(const bf16x8*)&Ac[(wr + m + im * 16) * TK + ck];
#pragma unroll
                for (int in_ = 0; in_ < 4; ++in_)
                    bfr[s][in_] = *(const bf16x8*)&Bc[(wc + m + in_ * 16) * TK + ck];
            }
            asm volatile("s_waitcnt lgkmcnt(0)" ::: "memory");
            __builtin_amdgcn_s_barrier();

            int tn = t_ + 2; if (tn > nk - 1) tn = nk - 1;
            int kk = tn * TK;
#pragma unroll
            for (int i = 0; i < 4; ++i) ld16(ag[i] + kk, &As[t_ & 1][(wv * 32 + i * 8) * TK]);
#pragma unroll
            for (int i = 0; i < 4; ++i) ld16(bg[i] + kk, &Bs[t_ & 1][(wv * 32 + i * 8) * TK]);

            __builtin_amdgcn_s_setprio(1);
#pragma unroll
            for (int s = 0; s < 2; ++s)
#pragma unroll
                for (int im = 0; im < 4; ++im)
#pragma unroll
                    for (int in_ = 0; in_ < 4; ++in_)
                        acc[im][in_] = __builtin_amdgcn_mfma_f32_16x16x32_bf16(
                            af[s][im], bfr[s][in_], acc[im][in_], 0, 0, 0);
            __builtin_amdgcn_s_setprio(0);
        }
        asm volatile("s_waitcnt vmcnt(0)" ::: "memory");
        __builtin_amdgcn_s_barrier();

#pragma unroll
        for (int im = 0; im < 4; ++im) {
#pragma unroll
            for (int j = 0; j < 4; ++j) {
                int row = wr + im * 16 + q * 4 + j;
                int gr = m0 + row;
                if (gr < cnt) {
                    int tok = list[e * N + gr];
                    float* orow = OUT + (size_t)tok * H + n0;
#pragma unroll
                    for (int in_ = 0; in_ < 4; ++in_) {
                        int col = wc + in_ * 16 + m;
                        orow[col] = acc[im][in_][j];
                    }
                }
            }
        }
    }
}

extern "C" void kernel_launch(void* const* d_in, const int* in_sizes, int n_in,
                              void* d_out, int out_size, void* d_ws, size_t ws_size,
                              hipStream_t stream) {
    const float* hidden   = (const float*)d_in[0];
    const int*   tok_ids  = (const int*)d_in[1];
    const float* mu       = (const float*)d_in[2];
    const float* gup      = (const float*)d_in[3];
    const float* dnp      = (const float*)d_in[4];
    const float* rw       = (const float*)d_in[5];
    float* out = (float*)d_out;

    int N  = in_sizes[1];                 // 8192
    int H  = in_sizes[0] / N;             // 1024
    int E  = in_sizes[5] / H;             // 8
    int F2 = in_sizes[3] / (E * H);       // 1024
    int Ie = F2 / 2;                      // 512

    int NB = (N + 255) / 256;             // 32

    char* ws = (char*)d_ws;
    size_t o = 0;
    auto alloc = [&](size_t sz) {
        size_t r = o;
        o += (sz + 255) & ~(size_t)255;
        return r;
    };
    int* counts   = (int*)(ws + alloc((size_t)E * 4));
    int* base_    = (int*)(ws + alloc((size_t)E * 4));
    int* eids     = (int*)(ws + alloc((size_t)N * 4));
    int* blockcnt = (int*)(ws + alloc((size_t)NB * 8 * 4));
    int* offs     = (int*)(ws + alloc((size_t)NB * 8 * 4));
    int* list     = (int*)(ws + alloc((size_t)E * N * 4));
    unsigned short* xb   = (unsigned short*)(ws + alloc((size_t)N * H * 2));
    unsigned short* wgut = (unsigned short*)(ws + alloc((size_t)E * F2 * H * 2));
    unsigned short* wdnt = (unsigned short*)(ws + alloc((size_t)E * H * Ie * 2));
    unsigned short* it   = (unsigned short*)(ws + alloc((size_t)N * Ie * 2));

    int NPREP = (N + 3) / 4;              // 2048
    int NTRANS = 2048 + 1024;             // gup tiles + dnp tiles
    k_prep_all<<<dim3(NPREP + NTRANS), dim3(256), 0, stream>>>(
        hidden, mu, tok_ids, rw, gup, dnp, xb, eids, wgut, wdnt, H, N, F2, Ie, NPREP);

    k_count<<<dim3(NB), dim3(256), 0, stream>>>(eids, blockcnt, N);
    k_scan<<<dim3(1), dim3(64), 0, stream>>>(blockcnt, counts, base_, offs, NB);
    k_scatter<<<dim3(NB), dim3(256), 0, stream>>>(eids, offs, list, N);

    // exact grids: 8 experts x (n-tiles) x 8 slots; slot-blocks loop over mt
    k_gemm_gateup<<<dim3(E * (Ie / 64) * 8), dim3(256), 0, stream>>>(
        xb, wgut, it, counts, base_, list, N, H, Ie);

    k_gemm_down<<<dim3(E * (H / TN) * 8), dim3(256), 0, stream>>>(
        it, wdnt, out, counts, base_, list, N, Ie, H);
}

// Round 7
// 218.034 us; speedup vs baseline: 1.0862x; 1.0561x over previous
//
#include <hip/hip_runtime.h>
#include <hip/hip_bf16.h>
#include <stdint.h>

typedef __bf16 bf16x8 __attribute__((ext_vector_type(8)));
typedef float f32x4 __attribute__((ext_vector_type(4)));
typedef unsigned short u16x8 __attribute__((ext_vector_type(8)));

#define ROUTE_BIAS_F 10.0f
#define VOCAB_SZ 32000

// ---------- helpers ----------
__device__ __forceinline__ unsigned short f2bf(float f) {
    union { float f; unsigned u; } v; v.f = f;
    unsigned u = v.u;
    unsigned r = u + 0x7FFFu + ((u >> 16) & 1u);   // RNE
    return (unsigned short)(r >> 16);
}
// async 16B global->LDS copy (lds dest wave-uniform; HW adds lane*16)
__device__ __forceinline__ void ld16(const unsigned short* g, unsigned short* l) {
    __builtin_amdgcn_global_load_lds(
        (const __attribute__((address_space(1))) void*)g,
        (__attribute__((address_space(3))) void*)l, 16, 0, 0);
}

// ---------- merged prep (router+convert) AND weight transpose ----------
// blocks [0, NPREP): one wave per token -> xb bf16 + eids.  Explicit-ILP form:
// all h/m loads preloaded, router weights double-buffered (VGPR 20 -> ~90 was
// the round-6 latency bottleneck: compiler serialized loads).
// blocks [NPREP, NPREP+1536): paired 64x64 transpose tiles (128 rows/block);
// tile-B global loads issued before tile-A LDS processing (latency hidden).
__global__ __launch_bounds__(256, 2) void k_prep_all(
        const float* __restrict__ hidden, const float* __restrict__ mu,
        const int* __restrict__ tok_ids, const float* __restrict__ rw,
        const float* __restrict__ gup, const float* __restrict__ dnp,
        unsigned short* __restrict__ xb, int* __restrict__ eids,
        unsigned short* __restrict__ wgut, unsigned short* __restrict__ wdnt,
        int H, int N, int F2, int Ie, int NPREP) {
    __shared__ float tile[64][65];
    int bid = blockIdx.x;
    int tid = threadIdx.x;

    if (bid < NPREP) {
        // ---- prep path: 4 tokens per block, 1 wave per token ----
        int lane = tid & 63;
        int wv   = tid >> 6;
        int tok  = bid * 4 + wv;
        if (tok >= N) return;
        const float4* hp = (const float4*)(hidden + (size_t)tok * H);
        const float4* mp = (const float4*)(mu + (size_t)tok * H);
        const float4* rp = (const float4*)rw;            // [8][H/4]
        ushort4* xp = (ushort4*)(xb + (size_t)tok * H);
        int H4 = H >> 2;                                 // 256

        float4 h4[4], m4[4];
#pragma unroll
        for (int j = 0; j < 4; ++j) {
            int idx = lane + 64 * j;
            h4[j] = hp[idx];
            m4[j] = mp[idx];
        }
#pragma unroll
        for (int j = 0; j < 4; ++j) {
            ushort4 o;
            o.x = f2bf(h4[j].x); o.y = f2bf(h4[j].y);
            o.z = f2bf(h4[j].z); o.w = f2bf(h4[j].w);
            xp[lane + 64 * j] = o;
        }

        float acc[8];
        float4 wn[4];
#pragma unroll
        for (int j = 0; j < 4; ++j) wn[j] = rp[lane + 64 * j];   // e=0 prefetch
#pragma unroll
        for (int e = 0; e < 8; ++e) {
            float4 wc[4];
#pragma unroll
            for (int j = 0; j < 4; ++j) wc[j] = wn[j];
            if (e < 7) {
#pragma unroll
                for (int j = 0; j < 4; ++j)
                    wn[j] = rp[(e + 1) * H4 + lane + 64 * j];
            }
            float a = 0.f;
#pragma unroll
            for (int j = 0; j < 4; ++j)
                a += m4[j].x * wc[j].x + m4[j].y * wc[j].y
                   + m4[j].z * wc[j].z + m4[j].w * wc[j].w;
            acc[e] = a;
        }
#pragma unroll
        for (int e = 0; e < 8; ++e) {
            float v = acc[e];
#pragma unroll
            for (int off = 32; off > 0; off >>= 1) v += __shfl_xor(v, off);
            acc[e] = v;
        }
        if (lane == 0) {
            int t = tok_ids[tok];
            if (t < 0) t = 0;
            if (t > VOCAB_SZ - 1) t = VOCAB_SZ - 1;
            int be = t % 8;
            float best = -1e30f; int bi = 0;
#pragma unroll
            for (int e = 0; e < 8; ++e) {
                float v = acc[e] + (e == be ? ROUTE_BIAS_F : 0.f);
                if (v > best) { best = v; bi = e; }
            }
            eids[tok] = bi;
        }
        return;
    }

    // ---- transpose path: paired 64x64 tiles (rows r0..r0+127, cols c0..c0+63)
    int tb = bid - NPREP;
    const float* inp; unsigned short* outp; int R, C, c0, r0;
    if (tb < 1024) {                      // gup: 8e x 16 c-tiles x 8 row-pairs
        int z = tb >> 7, t2 = tb & 127;
        R = H; C = F2;
        inp  = gup  + (size_t)z * R * C;
        outp = wgut + (size_t)z * R * C;  // [C][R]
        c0 = (t2 >> 3) * 64; r0 = (t2 & 7) * 128;
    } else {                              // dnp: 8e x 16 c-tiles x 4 row-pairs
        int tb2 = tb - 1024;
        int z = tb2 >> 6, t2 = tb2 & 63;
        R = Ie; C = H;
        inp  = dnp  + (size_t)z * R * C;
        outp = wdnt + (size_t)z * R * C;  // [C][R]
        c0 = (t2 >> 2) * 64; r0 = (t2 & 3) * 128;
    }
    {
        int tr = tid >> 4;              // 0..15
        int tc = (tid & 15) * 4;        // 0..60
        // issue BOTH tiles' loads up front: B's 4 loads hide under A's phase
        float4 va[4], vb[4];
#pragma unroll
        for (int p = 0; p < 4; ++p)
            va[p] = *(const float4*)&inp[(size_t)(r0 + tr + 16 * p) * C + c0 + tc];
#pragma unroll
        for (int p = 0; p < 4; ++p)
            vb[p] = *(const float4*)&inp[(size_t)(r0 + 64 + tr + 16 * p) * C + c0 + tc];

        // tile A
#pragma unroll
        for (int p = 0; p < 4; ++p) {
            tile[tr + 16 * p][tc + 0] = va[p].x;
            tile[tr + 16 * p][tc + 1] = va[p].y;
            tile[tr + 16 * p][tc + 2] = va[p].z;
            tile[tr + 16 * p][tc + 3] = va[p].w;
        }
        __syncthreads();
        int tr2 = tid >> 3;             // 0..31
        int tc2 = (tid & 7) * 8;        // 0..56
#pragma unroll
        for (int p = 0; p < 2; ++p) {
            int c = tr2 + 32 * p;
            u16x8 o;
#pragma unroll
            for (int j = 0; j < 8; ++j) o[j] = f2bf(tile[tc2 + j][c]);
            *(u16x8*)&outp[(size_t)(c0 + c) * R + r0 + tc2] = o;
        }
        __syncthreads();                // A reads done before overwrite

        // tile B
#pragma unroll
        for (int p = 0; p < 4; ++p) {
            tile[tr + 16 * p][tc + 0] = vb[p].x;
            tile[tr + 16 * p][tc + 1] = vb[p].y;
            tile[tr + 16 * p][tc + 2] = vb[p].z;
            tile[tr + 16 * p][tc + 3] = vb[p].w;
        }
        __syncthreads();
#pragma unroll
        for (int p = 0; p < 2; ++p) {
            int c = tr2 + 32 * p;
            u16x8 o;
#pragma unroll
            for (int j = 0; j < 8; ++j) o[j] = f2bf(tile[tc2 + j][c]);
            *(u16x8*)&outp[(size_t)(c0 + c) * R + r0 + 64 + tc2] = o;
        }
    }
}

// ---------- router phase B: STABLE parallel counting sort ----------
// Token-sorted per-expert lists are a PERF CONTRACT with the GEMMs: the
// A-gather (GEMM1) and OUT scatter (GEMM2) walk near-sequential rows only if
// the list is token-ordered. (Round-5 order-free atomic scatter: +19us on
// gateup from L2-miss latency on random gathers.)
__global__ void k_count(const int* __restrict__ eids,
                        int* __restrict__ blockcnt, int N) {
    __shared__ int cnt[8];
    int tid = threadIdx.x;
    if (tid < 8) cnt[tid] = 0;
    __syncthreads();
    int tok = blockIdx.x * 256 + tid;
    int lane = tid & 63;
    int eid = (tok < N) ? eids[tok] : -1;
#pragma unroll
    for (int e = 0; e < 8; ++e) {
        unsigned long long m = __ballot(eid == e);
        if (lane == 0 && m) atomicAdd(&cnt[e], __popcll(m));
    }
    __syncthreads();
    if (tid < 8) blockcnt[blockIdx.x * 8 + tid] = cnt[tid];
}

__global__ void k_scan(const int* __restrict__ blockcnt,
                       int* __restrict__ counts, int* __restrict__ base_,
                       int* __restrict__ offs, int NB) {   // NB == 32
    __shared__ int tot[8];
    int lane = threadIdx.x;
    int e = lane >> 3, g = lane & 7;
    int v[4];
    int s = 0;
#pragma unroll
    for (int i = 0; i < 4; ++i) { v[i] = s; s += blockcnt[(g * 4 + i) * 8 + e]; }
    int inc = s;
#pragma unroll
    for (int d = 1; d < 8; d <<= 1) {
        int t = __shfl_up(inc, d);
        if (g >= d) inc += t;
    }
    int excl = inc - s;
#pragma unroll
    for (int i = 0; i < 4; ++i) offs[(g * 4 + i) * 8 + e] = excl + v[i];
    if (g == 7) { counts[e] = inc; tot[e] = inc; }
    __syncthreads();
    if (lane == 0) {
        int s2 = 0;
#pragma unroll
        for (int i = 0; i < 8; ++i) { base_[i] = s2; s2 += tot[i]; }
    }
}

__global__ void k_scatter(const int* __restrict__ eids,
                          const int* __restrict__ offs,
                          int* __restrict__ list, int N) {
    __shared__ int wavecnt[4][8];
    int tid = threadIdx.x;
    int lane = tid & 63, wv = tid >> 6;
    int tok = blockIdx.x * 256 + tid;
    int eid = (tok < N) ? eids[tok] : -1;
    unsigned long long below = (1ull << lane) - 1ull;
    int myrank = 0;
#pragma unroll
    for (int e = 0; e < 8; ++e) {
        unsigned long long m = __ballot(eid == e);
        if (lane == 0) wavecnt[wv][e] = __popcll(m);
        if (eid == e) myrank = __popcll(m & below);
    }
    __syncthreads();
    if (eid >= 0) {
        int pre = 0;
        for (int w = 0; w < wv; ++w) pre += wavecnt[w][eid];
        int pos = offs[blockIdx.x * 8 + eid] + pre + myrank;
        list[eid * N + pos] = tok;
    }
}

// ---------- GEMM tile constants ----------
#define TM 128
#define TN 128
#define TK 64
// Counted-vmcnt depth-2 pipeline (T3+T4): per K-step
//   vmcnt(8) -> bar -> 16x ds_read_b128 frags -> lgkmcnt(0) -> bar
//   -> stage tile t+2 (8x ld16, stays in flight across MFMA) -> setprio(1)
//   -> 32 MFMA -> setprio(0).

// GEMM1 fused: IT[compact_row][Ie] = silu(gate)*up of gather(X) @ Wgu^T.
__global__ __launch_bounds__(256, 2) void k_gemm_gateup(
    const unsigned short* __restrict__ X,    // [N][H] bf16
    const unsigned short* __restrict__ Wt,   // [E][F2][H] bf16 (f-major)
    unsigned short* __restrict__ IT,         // [N][Ie] bf16 compact rows
    const int* __restrict__ counts, const int* __restrict__ base_,
    const int* __restrict__ list, int N, int H, int Ie) {
    int bid = blockIdx.x;
    int e = bid & 7;
    int t = bid >> 3;
    int nt = t & 7;                  // Ie/64 = 8 n-tiles
    int slot = t >> 3;               // 0..7
    int cnt = counts[e];
    int F2 = 2 * Ie;
    int b = base_[e];
    int nt64 = nt * 64;

    __shared__ __align__(16) unsigned short As[2][TM * TK];   // 2x16 KB
    __shared__ __align__(16) unsigned short Bs[2][TN * TK];   // 2x16 KB

    int tid = threadIdx.x;
    int lane = tid & 63, wv = tid >> 6;   // 4 waves
    int wr = (wv >> 1) * 64;
    int wc = (wv & 1) * 64;

    int rowg = lane >> 3;            // 0..7 row within 8-row group
    int sl   = (lane & 7) ^ rowg;    // swizzled source chunk for staging

    const unsigned short* bg[4];
#pragma unroll
    for (int i = 0; i < 4; ++i) {
        int r = wv * 32 + i * 8 + rowg;          // B tile row 0..127
        int wrow = (r & 1) * Ie + nt64 + (r >> 1);
        bg[i] = Wt + ((size_t)e * F2 + wrow) * H + sl * 8;
    }

    int q = lane >> 4, m = lane & 15;
    int sw = m & 7;
    int nk = H / TK;                 // 16

    for (int mt = slot; mt * TM < cnt; mt += 8) {
        int m0 = mt * TM;

        const unsigned short* ag[4];
#pragma unroll
        for (int i = 0; i < 4; ++i) {
            int r = wv * 32 + i * 8 + rowg;      // A tile row 0..127
            int gr = m0 + r;
            int tokrow = (gr < cnt) ? list[e * N + gr] : 0;
            ag[i] = X + (size_t)tokrow * H + sl * 8;
        }

        f32x4 acc[4][4];
#pragma unroll
        for (int i = 0; i < 4; ++i)
#pragma unroll
            for (int j = 0; j < 4; ++j) acc[i][j] = (f32x4)(0.f);

        // prologue: stage tile 0 -> buf0, tile 1 -> buf1 (16 loads in flight)
#pragma unroll
        for (int i = 0; i < 4; ++i) ld16(ag[i],      &As[0][(wv * 32 + i * 8) * TK]);
#pragma unroll
        for (int i = 0; i < 4; ++i) ld16(bg[i],      &Bs[0][(wv * 32 + i * 8) * TK]);
#pragma unroll
        for (int i = 0; i < 4; ++i) ld16(ag[i] + TK, &As[1][(wv * 32 + i * 8) * TK]);
#pragma unroll
        for (int i = 0; i < 4; ++i) ld16(bg[i] + TK, &Bs[1][(wv * 32 + i * 8) * TK]);

        for (int t_ = 0; t_ < nk; ++t_) {
            asm volatile("s_waitcnt vmcnt(8)" ::: "memory");
            __builtin_amdgcn_s_barrier();

            const unsigned short* Ac = As[t_ & 1];
            const unsigned short* Bc = Bs[t_ & 1];
            bf16x8 af[2][4], bfr[2][4];
#pragma unroll
            for (int s = 0; s < 2; ++s) {
                int ck = (((s * 4) + q) ^ sw) << 3;
#pragma unroll
                for (int im = 0; im < 4; ++im)
                    af[s][im] = *(const bf16x8*)&Ac[(wr + m + im * 16) * TK + ck];
#pragma unroll
                for (int in_ = 0; in_ < 4; ++in_)
                    bfr[s][in_] = *(const bf16x8*)&Bc[(wc + m + in_ * 16) * TK + ck];
            }
            asm volatile("s_waitcnt lgkmcnt(0)" ::: "memory");
            __builtin_amdgcn_s_barrier();   // all waves done reading buf[t_&1]

            int tn = t_ + 2; if (tn > nk - 1) tn = nk - 1;
            int kk = tn * TK;
#pragma unroll
            for (int i = 0; i < 4; ++i) ld16(ag[i] + kk, &As[t_ & 1][(wv * 32 + i * 8) * TK]);
#pragma unroll
            for (int i = 0; i < 4; ++i) ld16(bg[i] + kk, &Bs[t_ & 1][(wv * 32 + i * 8) * TK]);

            __builtin_amdgcn_s_setprio(1);
#pragma unroll
            for (int s = 0; s < 2; ++s)
#pragma unroll
                for (int im = 0; im < 4; ++im)
#pragma unroll
                    for (int in_ = 0; in_ < 4; ++in_)
                        acc[im][in_] = __builtin_amdgcn_mfma_f32_16x16x32_bf16(
                            af[s][im], bfr[s][in_], acc[im][in_], 0, 0, 0);
            __builtin_amdgcn_s_setprio(0);
        }
        asm volatile("s_waitcnt vmcnt(0)" ::: "memory");
        __builtin_amdgcn_s_barrier();

        // epilogue: pair even(gate)/odd(up) lanes, silu in fp32, write IT
#pragma unroll
        for (int im = 0; im < 4; ++im) {
#pragma unroll
            for (int j = 0; j < 4; ++j) {
                int row = wr + im * 16 + q * 4 + j;
                int gr = m0 + row;
#pragma unroll
                for (int in_ = 0; in_ < 4; ++in_) {
                    float v = acc[im][in_][j];
                    float u = __shfl_xor(v, 1);
                    float g = v;
                    float s = g / (1.f + __expf(-g));
                    float res = s * u;
                    if (!(lane & 1) && gr < cnt) {
                        int oc = nt64 + ((wc + in_ * 16 + m) >> 1);
                        IT[(size_t)(b + gr) * Ie + oc] = f2bf(res);
                    }
                }
            }
        }
    }
}

// GEMM2: OUT[token][H] = IT[compact_row][Ie] @ Wd^T, same pipeline.
__global__ __launch_bounds__(256, 2) void k_gemm_down(
    const unsigned short* __restrict__ IT,   // [N][Ie] bf16 compact
    const unsigned short* __restrict__ Wt,   // [E][H][Ie] bf16 (h-major)
    float* __restrict__ OUT,                 // [N][H] fp32 token-order
    const int* __restrict__ counts, const int* __restrict__ base_,
    const int* __restrict__ list, int N, int Ie, int H) {
    int bid = blockIdx.x;
    int e = bid & 7;
    int t = bid >> 3;
    int nt = t & 7;                  // H/TN = 8
    int slot = t >> 3;               // 0..7
    int cnt = counts[e];
    int n0 = nt * TN;
    int b = base_[e];

    __shared__ __align__(16) unsigned short As[2][TM * TK];
    __shared__ __align__(16) unsigned short Bs[2][TN * TK];

    int tid = threadIdx.x;
    int lane = tid & 63, wv = tid >> 6;
    int wr = (wv >> 1) * 64;
    int wc = (wv & 1) * 64;

    int rowg = lane >> 3;
    int sl   = (lane & 7) ^ rowg;

    const unsigned short* We = Wt + ((size_t)e * H + n0) * Ie;
    const unsigned short* bg[4];
#pragma unroll
    for (int i = 0; i < 4; ++i) {
        int r = wv * 32 + i * 8 + rowg;
        bg[i] = We + (size_t)r * Ie + sl * 8;
    }

    int q = lane >> 4, m = lane & 15;
    int sw = m & 7;
    int nk = Ie / TK;                // 8

    for (int mt = slot; mt * TM < cnt; mt += 8) {
        int m0 = mt * TM;

        const unsigned short* ag[4];
#pragma unroll
        for (int i = 0; i < 4; ++i) {
            int r = wv * 32 + i * 8 + rowg;
            int gr = m0 + r;
            int arow = (gr < cnt) ? (b + gr) : b;
            ag[i] = IT + (size_t)arow * Ie + sl * 8;
        }

        f32x4 acc[4][4];
#pragma unroll
        for (int i = 0; i < 4; ++i)
#pragma unroll
            for (int j = 0; j < 4; ++j) acc[i][j] = (f32x4)(0.f);

#pragma unroll
        for (int i = 0; i < 4; ++i) ld16(ag[i],      &As[0][(wv * 32 + i * 8) * TK]);
#pragma unroll
        for (int i = 0; i < 4; ++i) ld16(bg[i],      &Bs[0][(wv * 32 + i * 8) * TK]);
#pragma unroll
        for (int i = 0; i < 4; ++i) ld16(ag[i] + TK, &As[1][(wv * 32 + i * 8) * TK]);
#pragma unroll
        for (int i = 0; i < 4; ++i) ld16(bg[i] + TK, &Bs[1][(wv * 32 + i * 8) * TK]);

        for (int t_ = 0; t_ < nk; ++t_) {
            asm volatile("s_waitcnt vmcnt(8)" ::: "memory");
            __builtin_amdgcn_s_barrier();

            const unsigned short* Ac = As[t_ & 1];
            const unsigned short* Bc = Bs[t_ & 1];
            bf16x8 af[2][4], bfr[2][4];
#pragma unroll
            for (int s = 0; s < 2; ++s) {
                int ck = (((s * 4) + q) ^ sw) << 3;
#pragma unroll
                for (int im = 0; im < 4; ++im)
                    af[s][im] = *(const bf16x8*)&Ac[(wr + m + im * 16) * TK + ck];
#pragma unroll
                for (int in_ = 0; in_ < 4; ++in_)
                    bfr[s][in_] = *(const bf16x8*)&Bc[(wc + m + in_ * 16) * TK + ck];
            }
            asm volatile("s_waitcnt lgkmcnt(0)" ::: "memory");
            __builtin_amdgcn_s_barrier();

            int tn = t_ + 2; if (tn > nk - 1) tn = nk - 1;
            int kk = tn * TK;
#pragma unroll
            for (int i = 0; i < 4; ++i) ld16(ag[i] + kk, &As[t_ & 1][(wv * 32 + i * 8) * TK]);
#pragma unroll
            for (int i = 0; i < 4; ++i) ld16(bg[i] + kk, &Bs[t_ & 1][(wv * 32 + i * 8) * TK]);

            __builtin_amdgcn_s_setprio(1);
#pragma unroll
            for (int s = 0; s < 2; ++s)
#pragma unroll
                for (int im = 0; im < 4; ++im)
#pragma unroll
                    for (int in_ = 0; in_ < 4; ++in_)
                        acc[im][in_] = __builtin_amdgcn_mfma_f32_16x16x32_bf16(
                            af[s][im], bfr[s][in_], acc[im][in_], 0, 0, 0);
            __builtin_amdgcn_s_setprio(0);
        }
        asm volatile("s_waitcnt vmcnt(0)" ::: "memory");
        __builtin_amdgcn_s_barrier();

#pragma unroll
        for (int im = 0; im < 4; ++im) {
#pragma unroll
            for (int j = 0; j < 4; ++j) {
                int row = wr + im * 16 + q * 4 + j;
                int gr = m0 + row;
                if (gr < cnt) {
                    int tok = list[e * N + gr];
                    float* orow = OUT + (size_t)tok * H + n0;
#pragma unroll
                    for (int in_ = 0; in_ < 4; ++in_) {
                        int col = wc + in_ * 16 + m;
                        orow[col] = acc[im][in_][j];
                    }
                }
            }
        }
    }
}

extern "C" void kernel_launch(void* const* d_in, const int* in_sizes, int n_in,
                              void* d_out, int out_size, void* d_ws, size_t ws_size,
                              hipStream_t stream) {
    const float* hidden   = (const float*)d_in[0];
    const int*   tok_ids  = (const int*)d_in[1];
    const float* mu       = (const float*)d_in[2];
    const float* gup      = (const float*)d_in[3];
    const float* dnp      = (const float*)d_in[4];
    const float* rw       = (const float*)d_in[5];
    float* out = (float*)d_out;

    int N  = in_sizes[1];                 // 8192
    int H  = in_sizes[0] / N;             // 1024
    int E  = in_sizes[5] / H;             // 8
    int F2 = in_sizes[3] / (E * H);       // 1024
    int Ie = F2 / 2;                      // 512

    int NB = (N + 255) / 256;             // 32

    char* ws = (char*)d_ws;
    size_t o = 0;
    auto alloc = [&](size_t sz) {
        size_t r = o;
        o += (sz + 255) & ~(size_t)255;
        return r;
    };
    int* counts   = (int*)(ws + alloc((size_t)E * 4));
    int* base_    = (int*)(ws + alloc((size_t)E * 4));
    int* eids     = (int*)(ws + alloc((size_t)N * 4));
    int* blockcnt = (int*)(ws + alloc((size_t)NB * 8 * 4));
    int* offs     = (int*)(ws + alloc((size_t)NB * 8 * 4));
    int* list     = (int*)(ws + alloc((size_t)E * N * 4));
    unsigned short* xb   = (unsigned short*)(ws + alloc((size_t)N * H * 2));
    unsigned short* wgut = (unsigned short*)(ws + alloc((size_t)E * F2 * H * 2));
    unsigned short* wdnt = (unsigned short*)(ws + alloc((size_t)E * H * Ie * 2));
    unsigned short* it   = (unsigned short*)(ws + alloc((size_t)N * Ie * 2));

    int NPREP = (N + 3) / 4;              // 2048
    int NTRANS = 1024 + 512;              // gup row-pairs + dnp row-pairs
    k_prep_all<<<dim3(NPREP + NTRANS), dim3(256), 0, stream>>>(
        hidden, mu, tok_ids, rw, gup, dnp, xb, eids, wgut, wdnt, H, N, F2, Ie, NPREP);

    k_count<<<dim3(NB), dim3(256), 0, stream>>>(eids, blockcnt, N);
    k_scan<<<dim3(1), dim3(64), 0, stream>>>(blockcnt, counts, base_, offs, NB);
    k_scatter<<<dim3(NB), dim3(256), 0, stream>>>(eids, offs, list, N);

    // exact grids: 8 experts x (n-tiles) x 8 slots; slot-blocks loop over mt
    k_gemm_gateup<<<dim3(E * (Ie / 64) * 8), dim3(256), 0, stream>>>(
        xb, wgut, it, counts, base_, list, N, H, Ie);

    k_gemm_down<<<dim3(E * (H / TN) * 8), dim3(256), 0, stream>>>(
        it, wdnt, out, counts, base_, list, N, Ie, H);
}